// Round 18
// baseline (286.962 us; speedup 1.0000x reference)
//
#include <hip/hip_runtime.h>
#include <hip/hip_bf16.h>
#include <stdint.h>

// ---------------------------------------------------------------------------
// ConvAttention (B=2,S=4096,HID=1024,H=16,HD=64; conv k=(4,1) stride=(4,1))
// inputs f32, outputs f32; internal compute bf16 (round 3: absmax 0.0625).
// Round-18: single-variable probe on gemm_bt: __launch_bounds__(256,2) ->
// (256,4). Ledger says the two gemm launches run ~730 TF (94us for 68.7GF);
// hypothesis: acc(64)+frags(32)+addr regs ~130-160 VGPR -> 3 waves/SIMD;
// forcing <=128 VGPR lifts occupancy to 4 blocks/CU (m114: m97-structure
// overlap improves with resident waves). Core loop needs ~96 VGPR so a
// clean 128 fit is plausible. Everything else byte-identical to round 17
// (281.5us: staging win confirmed).
// Pipeline:
//   0. q f32 -> Xb bf16;  1. convT4 W* (one launch)
//   2. merged QKV gemm (z=0 Q x exp(-lt); z=1/2 conv -> Kc/Vc)
//   3. Vc -> Vct;  4. fused attn (r17 staging);  5. out0 = oattn @ Wlin
// ---------------------------------------------------------------------------

using short8 = __attribute__((ext_vector_type(8))) short;
using bf16x4 = __attribute__((ext_vector_type(4))) short;
using f32x4  = __attribute__((ext_vector_type(4))) float;

__device__ __forceinline__ float bf2f(short u) {
  union { float f; uint32_t i; } v; v.i = ((uint32_t)(uint16_t)u) << 16; return v.f;
}
__device__ __forceinline__ short f2bf(float f) {
  union { float f; uint32_t i; } v; v.f = f;
  uint32_t r = v.i + 0x7FFFu + ((v.i >> 16) & 1u);   // RNE
  return (short)(uint16_t)(r >> 16);
}
__device__ __forceinline__ short f2bf_hw(float f) {
  __hip_bfloat16 h = __float2bfloat16(f);             // hw cvt, pairs fuse
  return *reinterpret_cast<short*>(&h);
}

__device__ __forceinline__ void async16(const void* g, void* l) {
  __builtin_amdgcn_global_load_lds(
      (const __attribute__((address_space(1))) void*)g,
      (__attribute__((address_space(3))) void*)l, 16, 0, 0);
}

// ---------------------------------------------------------------------------
__global__ void cvt8(const float* __restrict__ in, short* __restrict__ out) {
  const size_t i = ((size_t)blockIdx.x * 256 + threadIdx.x) * 8;
  float4 a = *(const float4*)(in + i);
  float4 b = *(const float4*)(in + i + 4);
  short8 o;
  o[0] = f2bf(a.x); o[1] = f2bf(a.y); o[2] = f2bf(a.z); o[3] = f2bf(a.w);
  o[4] = f2bf(b.x); o[5] = f2bf(b.y); o[6] = f2bf(b.z); o[7] = f2bf(b.w);
  *(short8*)(out + i) = o;
}

// ---------------------------------------------------------------------------
struct ConvT4Args { const float* s0; const float* s1; const float* s2;
                    const float* s3; short* out; };
__global__ void convT4(ConvT4Args a) {
  __shared__ float tile[64][65];
  const float* in = (blockIdx.z == 0) ? a.s0 : (blockIdx.z == 1) ? a.s1
                   : (blockIdx.z == 2) ? a.s2 : a.s3;
  short* out = a.out + (size_t)blockIdx.z * 1048576;
  const int c0 = blockIdx.x * 64, r0 = blockIdx.y * 64;
  const int tx = threadIdx.x & 63, ty = threadIdx.x >> 6;
  #pragma unroll
  for (int i = ty; i < 64; i += 4)
    tile[i][tx] = in[(size_t)(r0 + i) * 1024 + c0 + tx];
  __syncthreads();
  #pragma unroll
  for (int i = ty; i < 64; i += 4)
    out[(size_t)(c0 + i) * 1024 + r0 + tx] = f2bf(tile[tx][i]);
}

// ---------------------------------------------------------------------------
__global__ void transpose2d(const short* __restrict__ in, short* __restrict__ out,
                            int R, int C) {
  __shared__ short tile[64][65];
  const size_t zoff = (size_t)blockIdx.z * (size_t)R * (size_t)C;
  const int c0 = blockIdx.x * 64, r0 = blockIdx.y * 64;
  const int tx = threadIdx.x & 63, ty = threadIdx.x >> 6;
  #pragma unroll
  for (int i = ty; i < 64; i += 4)
    tile[i][tx] = in[zoff + (size_t)(r0 + i) * C + c0 + tx];
  __syncthreads();
  #pragma unroll
  for (int i = ty; i < 64; i += 4)
    out[zoff + (size_t)(c0 + i) * R + r0 + tx] = tile[tx][i];
}

// ---------------------------------------------------------------------------
// C = A[M][K] * Bt[N][K]^T, bf16 inputs, f32 accum. 128x128 tile, BK=64.
// mode 0: f32 row-major -> Cf
// mode 3: merged QKV: z=0 head-major bf16 x exp(-lt); z=1/2 conv -> Kc/Vc
struct GemmArgs {
  const short* A; const short* Bt;
  short* C; short* C2; short* C3; float* Cf;
  long sA, sB, sC;
  long zA, zB, zC;
  int  K;
  const float* ltemp;
  const float* cw;
  int  mode;
};

__global__ __launch_bounds__(256, 4)
void gemm_bt(GemmArgs g) {
  const int tid  = threadIdx.x;
  const int wave = tid >> 6, lane = tid & 63;
  const int l16 = lane & 15, l4 = lane >> 4;
  const int wm = wave & 1, wn = wave >> 1;
  const int m0 = blockIdx.y * 128, n0 = blockIdx.x * 128;
  const size_t zA = (size_t)blockIdx.z * g.zA;
  const size_t zB = (size_t)blockIdx.z * g.zB;
  const size_t zC = (size_t)blockIdx.z * g.zC;

  __shared__ __align__(16) short As[128 * 64];
  __shared__ __align__(16) short Bs[128 * 64];

  f32x4 acc[4][4] = {};

  const int srow = tid >> 3;
  const int scol = (tid & 7) << 3;
  const short* Abase = g.A + zA + (size_t)m0 * g.sA + scol;
  const short* Bbase = g.Bt + zB + (size_t)n0 * g.sB + scol;

  for (int k0 = 0; k0 < g.K; k0 += 64) {
    __syncthreads();
    #pragma unroll
    for (int c = 0; c < 4; ++c) {
      async16(Abase + (size_t)(c * 32 + srow) * g.sA + k0, &As[c * 2048 + wave * 512]);
      async16(Bbase + (size_t)(c * 32 + srow) * g.sB + k0, &Bs[c * 2048 + wave * 512]);
    }
    asm volatile("s_waitcnt vmcnt(0)" ::: "memory");
    __syncthreads();
    #pragma unroll
    for (int kk = 0; kk < 2; ++kk) {
      short8 a[4], b[4];
      #pragma unroll
      for (int t = 0; t < 4; ++t) {
        a[t] = *(const short8*)&As[(wm * 64 + t * 16 + l16) * 64 + kk * 32 + l4 * 8];
        b[t] = *(const short8*)&Bs[(wn * 64 + t * 16 + l16) * 64 + kk * 32 + l4 * 8];
      }
      #pragma unroll
      for (int i = 0; i < 4; ++i)
        #pragma unroll
        for (int j = 0; j < 4; ++j)
          acc[i][j] = __builtin_amdgcn_mfma_f32_16x16x32_bf16(a[i], b[j], acc[i][j], 0, 0, 0);
    }
  }

  if (g.mode == 0) {
    float* Cz = g.Cf + zC;
    #pragma unroll
    for (int i = 0; i < 4; ++i) {
      const int row = m0 + wm * 64 + i * 16 + l4 * 4;
      #pragma unroll
      for (int j = 0; j < 4; ++j) {
        const int col = n0 + wn * 64 + j * 16 + l16;
        #pragma unroll
        for (int rr = 0; rr < 4; ++rr)
          Cz[(size_t)(row + rr) * g.sC + col] = acc[i][j][rr];
      }
    }
  } else if (blockIdx.z == 0) {
    float sc = __expf(-g.ltemp[0]);
    short* Cz = g.C;
    #pragma unroll
    for (int i = 0; i < 4; ++i) {
      const int row = m0 + wm * 64 + i * 16 + l4 * 4;
      #pragma unroll
      for (int j = 0; j < 4; ++j) {
        const int col = n0 + wn * 64 + j * 16 + l16;
        const int hh = col >> 6, dd = col & 63;
        #pragma unroll
        for (int rr = 0; rr < 4; ++rr) {
          const int m = row + rr;
          const size_t off = (size_t)((m >> 12) * 16 + hh) * 262144
                           + (size_t)(m & 4095) * 64 + dd;
          Cz[off] = f2bf(acc[i][j][rr] * sc);
        }
      }
    }
  } else {
    const int h = (n0 + wn * 64) >> 6;
    float wv[4];
    #pragma unroll
    for (int t = 0; t < 4; ++t) wv[t] = g.cw[h * 4 + t];
    short* dst = (blockIdx.z == 1) ? g.C2 : g.C3;
    #pragma unroll
    for (int i = 0; i < 4; ++i) {
      const int row_base = m0 + wm * 64 + i * 16 + l4 * 4;
      const int b  = row_base >> 12;
      const int sk = (row_base & 4095) >> 2;
      #pragma unroll
      for (int j = 0; j < 4; ++j) {
        const int d = j * 16 + l16;
        float v = wv[0] * acc[i][j][0] + wv[1] * acc[i][j][1]
                + wv[2] * acc[i][j][2] + wv[3] * acc[i][j][3];
        dst[(size_t)(b * 16 + h) * 65536 + (size_t)sk * 64 + d] = f2bf(v);
      }
    }
  }
}

// ---------------------------------------------------------------------------
// fused logits + max-free softmax + PV with block-shared LDS K/V staging
// (r17, unchanged). grid 1024 (bh = id&31 XCD-pinned); block = 128 q.
// 16 half-sections of 64 k, double-buffered; stage loads issued BEFORE the
// consume phase's stores -> vmcnt(8) retires loads, leaves stores in flight.
__global__ __launch_bounds__(256, 3)
void fused_attn(const short* __restrict__ qh, const short* __restrict__ kc,
                const short* __restrict__ vct,
                float* __restrict__ logits, short* __restrict__ oattn) {
  const int id = blockIdx.x;
  const int bh = id & 31;                 // XCD-pinned: id%8 == bh%8
  const int qt = id >> 5;
  const int tid = threadIdx.x;
  const int wave = tid >> 6, lane = tid & 63;
  const int l16 = lane & 15, l4 = lane >> 4;

  __shared__ __align__(16) short Ks[2][4096];     // [64 k-rows][64 d], 8KB x2
  __shared__ __align__(16) short Vs[2][4096];     // [64 d-rows][64 k], 8KB x2
  __shared__ __align__(16) short attb[4][2048];   // P: [32 q][64 k]/wave, 4KB
  short* const myatt = attb[wave];

  const int qg = qt * 128 + wave * 32;    // wave's q-row base (32 rows)

  const short* qbase = qh + (size_t)bh * 262144 + (size_t)qg * 64;
  const short8 aQ0_0 = *(const short8*)(qbase + (size_t)l16 * 64 + l4 * 8);
  const short8 aQ0_1 = *(const short8*)(qbase + (size_t)l16 * 64 + 32 + l4 * 8);
  const short8 aQ1_0 = *(const short8*)(qbase + (size_t)(16 + l16) * 64 + l4 * 8);
  const short8 aQ1_1 = *(const short8*)(qbase + (size_t)(16 + l16) * 64 + 32 + l4 * 8);

  const short* kb = kc + (size_t)bh * 65536;
  const short* vb = vct + (size_t)bh * 65536;
  float* lgqA = logits + (size_t)bh * 4194304 + (size_t)(qg + l16) * 1024;
  float* lgqB = lgqA + 16 * 1024;

  const int strow = tid >> 3;                    // 0..31
  const int schunk = (tid & 7) ^ (strow & 7);    // pre-swizzled global chunk
  const int sdst = tid * 8;                      // LDS shorts (linear)

  const int sw = (l16 & 7) << 3;          // att/K/V read XOR (elem units)
  float psumA = 0.f, psumB = 0.f;
  f32x4 o0 = {}, o1 = {}, o2 = {}, o3 = {};
  f32x4 o4 = {}, o5 = {}, o6 = {}, o7 = {};

  short* ksc = Ks[0]; short* ksn = Ks[1];
  short* vsc = Vs[0]; short* vsn = Vs[1];

  #pragma unroll
  for (int ri = 0; ri < 2; ++ri) {
    const int row = ri * 32 + strow;
    async16(kb + (size_t)row * 64 + schunk * 8, ksc + ri * 2048 + sdst);
    async16(vb + (size_t)row * 1024 + schunk * 8, vsc + ri * 2048 + sdst);
  }
  asm volatile("s_waitcnt vmcnt(0)" ::: "memory");
  __syncthreads();

  for (int hs = 0; hs < 16; ++hs) {
    const int kbase = hs * 64;

    if (hs < 15) {
      #pragma unroll
      for (int ri = 0; ri < 2; ++ri) {
        const int row = ri * 32 + strow;
        async16(kb + (size_t)(kbase + 64 + row) * 64 + schunk * 8,
                ksn + ri * 2048 + sdst);
        async16(vb + (size_t)row * 1024 + (kbase + 64) + schunk * 8,
                vsn + ri * 2048 + sdst);
      }
    }

    #pragma unroll
    for (int j = 0; j < 4; ++j) {
      const int row = j * 16 + l16;
      short8 k0 = *(const short8*)&ksc[row * 64 + ((l4 ^ (l16 & 7)) << 3)];
      short8 k1 = *(const short8*)&ksc[row * 64 + (((4 + l4) ^ (l16 & 7)) << 3)];
      f32x4 accA = {}, accB = {};
      accA = __builtin_amdgcn_mfma_f32_16x16x32_bf16(k0, aQ0_0, accA, 0, 0, 0);
      accA = __builtin_amdgcn_mfma_f32_16x16x32_bf16(k1, aQ0_1, accA, 0, 0, 0);
      accB = __builtin_amdgcn_mfma_f32_16x16x32_bf16(k0, aQ1_0, accB, 0, 0, 0);
      accB = __builtin_amdgcn_mfma_f32_16x16x32_bf16(k1, aQ1_1, accB, 0, 0, 0);

      *(f32x4*)(lgqA + kbase + j * 16 + l4 * 4) = accA;
      *(f32x4*)(lgqB + kbase + j * 16 + l4 * 4) = accB;

      bf16x4 pA, pB;
      #pragma unroll
      for (int rr = 0; rr < 4; ++rr) {
        const float eA = __expf(accA[rr]);
        const float eB = __expf(accB[rr]);
        psumA += eA;
        psumB += eB;
        pA[rr] = f2bf_hw(eA);
        pB[rr] = f2bf_hw(eB);
      }
      const int pc = (j * 16 + l4 * 4) ^ sw;
      *(bf16x4*)&myatt[l16 * 64 + pc] = pA;
      *(bf16x4*)&myatt[(16 + l16) * 64 + pc] = pB;
    }

    #pragma unroll
    for (int c = 0; c < 2; ++c) {
      const int cl = (c * 32 + l4 * 8) ^ sw;
      const int vch = ((c * 4 + l4) ^ (l16 & 7)) << 3;
      short8 paA = *(const short8*)&myatt[l16 * 64 + cl];
      short8 paB = *(const short8*)&myatt[(16 + l16) * 64 + cl];
      short8 v0 = *(const short8*)&vsc[(l16) * 64 + vch];
      short8 v1 = *(const short8*)&vsc[(16 + l16) * 64 + vch];
      short8 v2 = *(const short8*)&vsc[(32 + l16) * 64 + vch];
      short8 v3 = *(const short8*)&vsc[(48 + l16) * 64 + vch];
      o0 = __builtin_amdgcn_mfma_f32_16x16x32_bf16(paA, v0, o0, 0, 0, 0);
      o1 = __builtin_amdgcn_mfma_f32_16x16x32_bf16(paA, v1, o1, 0, 0, 0);
      o2 = __builtin_amdgcn_mfma_f32_16x16x32_bf16(paA, v2, o2, 0, 0, 0);
      o3 = __builtin_amdgcn_mfma_f32_16x16x32_bf16(paA, v3, o3, 0, 0, 0);
      o4 = __builtin_amdgcn_mfma_f32_16x16x32_bf16(paB, v0, o4, 0, 0, 0);
      o5 = __builtin_amdgcn_mfma_f32_16x16x32_bf16(paB, v1, o5, 0, 0, 0);
      o6 = __builtin_amdgcn_mfma_f32_16x16x32_bf16(paB, v2, o6, 0, 0, 0);
      o7 = __builtin_amdgcn_mfma_f32_16x16x32_bf16(paB, v3, o7, 0, 0, 0);
    }

    if (hs < 15) {
      asm volatile("s_waitcnt vmcnt(8)" ::: "memory");
      __syncthreads();
      short* t;
      t = ksc; ksc = ksn; ksn = t;
      t = vsc; vsc = vsn; vsn = t;
    }
  }

  psumA += __shfl_xor(psumA, 16, 64);
  psumA += __shfl_xor(psumA, 32, 64);
  psumB += __shfl_xor(psumB, 16, 64);
  psumB += __shfl_xor(psumB, 32, 64);
  float invA[4], invB[4];
  #pragma unroll
  for (int rr = 0; rr < 4; ++rr) {
    invA[rr] = 1.0f / __shfl(psumA, l4 * 4 + rr, 64);
    invB[rr] = 1.0f / __shfl(psumB, l4 * 4 + rr, 64);
  }

  short* op = oattn + ((size_t)(bh >> 4) * 4096 + qg) * 1024 + (bh & 15) * 64;
  #pragma unroll
  for (int rr = 0; rr < 4; ++rr) {
    const size_t ra = (size_t)(l4 * 4 + rr) * 1024;
    op[ra + l16]      = f2bf(o0[rr] * invA[rr]);
    op[ra + 16 + l16] = f2bf(o1[rr] * invA[rr]);
    op[ra + 32 + l16] = f2bf(o2[rr] * invA[rr]);
    op[ra + 48 + l16] = f2bf(o3[rr] * invA[rr]);
    const size_t rb = (size_t)(16 + l4 * 4 + rr) * 1024;
    op[rb + l16]      = f2bf(o4[rr] * invB[rr]);
    op[rb + 16 + l16] = f2bf(o5[rr] * invB[rr]);
    op[rb + 32 + l16] = f2bf(o6[rr] * invB[rr]);
    op[rb + 48 + l16] = f2bf(o7[rr] * invB[rr]);
  }
}

// ---------------------------------------------------------------------------
extern "C" void kernel_launch(void* const* d_in, const int* in_sizes, int n_in,
                              void* d_out, int out_size, void* d_ws, size_t ws_size,
                              hipStream_t stream) {
  const float* q    = (const float*)d_in[0];
  const float* Wq   = (const float*)d_in[1];
  const float* Wk   = (const float*)d_in[2];
  const float* Wv   = (const float*)d_in[3];
  const float* Wlin = (const float*)d_in[4];
  const float* cw   = (const float*)d_in[5];
  const float* lt   = (const float*)d_in[6];

  float* out_f    = (float*)d_out;             // output 0: [8192][1024] f32
  float* logits_f = out_f + 8388608;           // output 1: [32][4096][1024] f32

  short* ws    = (short*)d_ws;
  short* Wt    = ws;                 // 4 x 1048576
  short* Xb    = ws + 4194304;       // 8388608 ; reused as oattn
  short* QKVq  = ws + 12582912;      // 8388608 head-major Q (pre-scaled)
  short* Kc    = ws + 20971520;      // [32][1024][64]
  short* Vc    = ws + 23068672;      // [32][1024][64]
  short* Vct   = ws + 25165824;      // [32][64][1024]
  short* oattn = Xb;
  // total 27,262,976 shorts = 54.5 MB

  cvt8<<<dim3(4096), 256, 0, stream>>>(q, Xb);

  ConvT4Args ca = { Wq, Wk, Wv, Wlin, Wt };
  convT4<<<dim3(16, 16, 4), 256, 0, stream>>>(ca);

  GemmArgs gq = {};
  gq.A = Xb; gq.Bt = Wt; gq.C = QKVq; gq.C2 = Kc; gq.C3 = Vc;
  gq.sA = 1024; gq.sB = 1024; gq.sC = 0;
  gq.zA = 0; gq.zB = 1048576; gq.zC = 0;
  gq.K = 1024; gq.ltemp = lt; gq.cw = cw; gq.mode = 3;
  gemm_bt<<<dim3(8, 64, 3), 256, 0, stream>>>(gq);

  transpose2d<<<dim3(1, 16, 32), 256, 0, stream>>>(Vc, Vct, 1024, 64);

  fused_attn<<<dim3(1024), 256, 0, stream>>>(QKVq, Kc, Vct, logits_f, oattn);

  GemmArgs gf = {};
  gf.A = oattn; gf.Bt = Wt + 3145728; gf.Cf = out_f;
  gf.sA = 1024; gf.sB = 1024; gf.sC = 1024;
  gf.zA = 0; gf.zB = 0; gf.zC = 0;
  gf.K = 1024; gf.mode = 0;
  gemm_bt<<<dim3(8, 64, 1), 256, 0, stream>>>(gf);
}

// Round 19
// 285.694 us; speedup vs baseline: 1.0044x; 1.0044x over previous
//
#include <hip/hip_runtime.h>
#include <hip/hip_bf16.h>
#include <stdint.h>

// ---------------------------------------------------------------------------
// ConvAttention (B=2,S=4096,HID=1024,H=16,HD=64; conv k=(4,1) stride=(4,1))
// inputs f32, outputs f32; internal compute bf16 (round 3: absmax 0.0625).
// Round-19: r18's gemm bounds(256,4) regressed (spill) -> reverted to (256,2).
// fused_attn residency fix: 48KB LDS = 3 blocks/CU -> 1024 blocks run in TWO
// rounds (768+256; round 2 wastes 2/3 of each CU). Single-buffer the V tile
// (V(hs) consumed only in PV, after QK(hs)): stage V(hs)+K(hs+1) at section
// start, QK(hs) on resident Ks, vmcnt(8) retires the 4 loads (8 younger
// logit stores stay in flight), barrier, PV(hs), barrier. LDS 40KB ->
// 4 blocks/CU -> exactly ONE residency round; launch_bounds(256,4).
// Pipeline:
//   0. q f32 -> Xb bf16;  1. convT4 W* (one launch)
//   2. merged QKV gemm (z=0 Q x exp(-lt); z=1/2 conv -> Kc/Vc)
//   3. Vc -> Vct;  4. fused attn;  5. out0 = oattn @ Wlin
// ---------------------------------------------------------------------------

using short8 = __attribute__((ext_vector_type(8))) short;
using bf16x4 = __attribute__((ext_vector_type(4))) short;
using f32x4  = __attribute__((ext_vector_type(4))) float;

__device__ __forceinline__ float bf2f(short u) {
  union { float f; uint32_t i; } v; v.i = ((uint32_t)(uint16_t)u) << 16; return v.f;
}
__device__ __forceinline__ short f2bf(float f) {
  union { float f; uint32_t i; } v; v.f = f;
  uint32_t r = v.i + 0x7FFFu + ((v.i >> 16) & 1u);   // RNE
  return (short)(uint16_t)(r >> 16);
}
__device__ __forceinline__ short f2bf_hw(float f) {
  __hip_bfloat16 h = __float2bfloat16(f);             // hw cvt, pairs fuse
  return *reinterpret_cast<short*>(&h);
}

__device__ __forceinline__ void async16(const void* g, void* l) {
  __builtin_amdgcn_global_load_lds(
      (const __attribute__((address_space(1))) void*)g,
      (__attribute__((address_space(3))) void*)l, 16, 0, 0);
}

// ---------------------------------------------------------------------------
__global__ void cvt8(const float* __restrict__ in, short* __restrict__ out) {
  const size_t i = ((size_t)blockIdx.x * 256 + threadIdx.x) * 8;
  float4 a = *(const float4*)(in + i);
  float4 b = *(const float4*)(in + i + 4);
  short8 o;
  o[0] = f2bf(a.x); o[1] = f2bf(a.y); o[2] = f2bf(a.z); o[3] = f2bf(a.w);
  o[4] = f2bf(b.x); o[5] = f2bf(b.y); o[6] = f2bf(b.z); o[7] = f2bf(b.w);
  *(short8*)(out + i) = o;
}

// ---------------------------------------------------------------------------
struct ConvT4Args { const float* s0; const float* s1; const float* s2;
                    const float* s3; short* out; };
__global__ void convT4(ConvT4Args a) {
  __shared__ float tile[64][65];
  const float* in = (blockIdx.z == 0) ? a.s0 : (blockIdx.z == 1) ? a.s1
                   : (blockIdx.z == 2) ? a.s2 : a.s3;
  short* out = a.out + (size_t)blockIdx.z * 1048576;
  const int c0 = blockIdx.x * 64, r0 = blockIdx.y * 64;
  const int tx = threadIdx.x & 63, ty = threadIdx.x >> 6;
  #pragma unroll
  for (int i = ty; i < 64; i += 4)
    tile[i][tx] = in[(size_t)(r0 + i) * 1024 + c0 + tx];
  __syncthreads();
  #pragma unroll
  for (int i = ty; i < 64; i += 4)
    out[(size_t)(c0 + i) * 1024 + r0 + tx] = f2bf(tile[tx][i]);
}

// ---------------------------------------------------------------------------
__global__ void transpose2d(const short* __restrict__ in, short* __restrict__ out,
                            int R, int C) {
  __shared__ short tile[64][65];
  const size_t zoff = (size_t)blockIdx.z * (size_t)R * (size_t)C;
  const int c0 = blockIdx.x * 64, r0 = blockIdx.y * 64;
  const int tx = threadIdx.x & 63, ty = threadIdx.x >> 6;
  #pragma unroll
  for (int i = ty; i < 64; i += 4)
    tile[i][tx] = in[zoff + (size_t)(r0 + i) * C + c0 + tx];
  __syncthreads();
  #pragma unroll
  for (int i = ty; i < 64; i += 4)
    out[zoff + (size_t)(c0 + i) * R + r0 + tx] = tile[tx][i];
}

// ---------------------------------------------------------------------------
// C = A[M][K] * Bt[N][K]^T, bf16 inputs, f32 accum. 128x128 tile, BK=64.
// mode 0: f32 row-major -> Cf
// mode 3: merged QKV: z=0 head-major bf16 x exp(-lt); z=1/2 conv -> Kc/Vc
struct GemmArgs {
  const short* A; const short* Bt;
  short* C; short* C2; short* C3; float* Cf;
  long sA, sB, sC;
  long zA, zB, zC;
  int  K;
  const float* ltemp;
  const float* cw;
  int  mode;
};

__global__ __launch_bounds__(256, 2)
void gemm_bt(GemmArgs g) {
  const int tid  = threadIdx.x;
  const int wave = tid >> 6, lane = tid & 63;
  const int l16 = lane & 15, l4 = lane >> 4;
  const int wm = wave & 1, wn = wave >> 1;
  const int m0 = blockIdx.y * 128, n0 = blockIdx.x * 128;
  const size_t zA = (size_t)blockIdx.z * g.zA;
  const size_t zB = (size_t)blockIdx.z * g.zB;
  const size_t zC = (size_t)blockIdx.z * g.zC;

  __shared__ __align__(16) short As[128 * 64];
  __shared__ __align__(16) short Bs[128 * 64];

  f32x4 acc[4][4] = {};

  const int srow = tid >> 3;
  const int scol = (tid & 7) << 3;
  const short* Abase = g.A + zA + (size_t)m0 * g.sA + scol;
  const short* Bbase = g.Bt + zB + (size_t)n0 * g.sB + scol;

  for (int k0 = 0; k0 < g.K; k0 += 64) {
    __syncthreads();
    #pragma unroll
    for (int c = 0; c < 4; ++c) {
      async16(Abase + (size_t)(c * 32 + srow) * g.sA + k0, &As[c * 2048 + wave * 512]);
      async16(Bbase + (size_t)(c * 32 + srow) * g.sB + k0, &Bs[c * 2048 + wave * 512]);
    }
    asm volatile("s_waitcnt vmcnt(0)" ::: "memory");
    __syncthreads();
    #pragma unroll
    for (int kk = 0; kk < 2; ++kk) {
      short8 a[4], b[4];
      #pragma unroll
      for (int t = 0; t < 4; ++t) {
        a[t] = *(const short8*)&As[(wm * 64 + t * 16 + l16) * 64 + kk * 32 + l4 * 8];
        b[t] = *(const short8*)&Bs[(wn * 64 + t * 16 + l16) * 64 + kk * 32 + l4 * 8];
      }
      #pragma unroll
      for (int i = 0; i < 4; ++i)
        #pragma unroll
        for (int j = 0; j < 4; ++j)
          acc[i][j] = __builtin_amdgcn_mfma_f32_16x16x32_bf16(a[i], b[j], acc[i][j], 0, 0, 0);
    }
  }

  if (g.mode == 0) {
    float* Cz = g.Cf + zC;
    #pragma unroll
    for (int i = 0; i < 4; ++i) {
      const int row = m0 + wm * 64 + i * 16 + l4 * 4;
      #pragma unroll
      for (int j = 0; j < 4; ++j) {
        const int col = n0 + wn * 64 + j * 16 + l16;
        #pragma unroll
        for (int rr = 0; rr < 4; ++rr)
          Cz[(size_t)(row + rr) * g.sC + col] = acc[i][j][rr];
      }
    }
  } else if (blockIdx.z == 0) {
    float sc = __expf(-g.ltemp[0]);
    short* Cz = g.C;
    #pragma unroll
    for (int i = 0; i < 4; ++i) {
      const int row = m0 + wm * 64 + i * 16 + l4 * 4;
      #pragma unroll
      for (int j = 0; j < 4; ++j) {
        const int col = n0 + wn * 64 + j * 16 + l16;
        const int hh = col >> 6, dd = col & 63;
        #pragma unroll
        for (int rr = 0; rr < 4; ++rr) {
          const int m = row + rr;
          const size_t off = (size_t)((m >> 12) * 16 + hh) * 262144
                           + (size_t)(m & 4095) * 64 + dd;
          Cz[off] = f2bf(acc[i][j][rr] * sc);
        }
      }
    }
  } else {
    const int h = (n0 + wn * 64) >> 6;
    float wv[4];
    #pragma unroll
    for (int t = 0; t < 4; ++t) wv[t] = g.cw[h * 4 + t];
    short* dst = (blockIdx.z == 1) ? g.C2 : g.C3;
    #pragma unroll
    for (int i = 0; i < 4; ++i) {
      const int row_base = m0 + wm * 64 + i * 16 + l4 * 4;
      const int b  = row_base >> 12;
      const int sk = (row_base & 4095) >> 2;
      #pragma unroll
      for (int j = 0; j < 4; ++j) {
        const int d = j * 16 + l16;
        float v = wv[0] * acc[i][j][0] + wv[1] * acc[i][j][1]
                + wv[2] * acc[i][j][2] + wv[3] * acc[i][j][3];
        dst[(size_t)(b * 16 + h) * 65536 + (size_t)sk * 64 + d] = f2bf(v);
      }
    }
  }
}

// ---------------------------------------------------------------------------
// fused logits + max-free softmax + PV; K double-buffered, V single-buffered.
// grid 1024 (bh = id&31 XCD-pinned); block = 128 q (4 waves x 32).
// LDS 40KB -> 4 blocks/CU -> ONE residency round.
// Per section hs (16 of 64 k):
//   stage V(hs) + K(hs+1) -> QK(hs) on Ks cur (8 logit stores, exp->att)
//   -> vmcnt(8) [retires the 4 loads, leaves 8 younger stores] -> barrier
//   -> PV(hs) on Vs -> barrier [protect Vs/Ks before next stage].
__global__ __launch_bounds__(256, 4)
void fused_attn(const short* __restrict__ qh, const short* __restrict__ kc,
                const short* __restrict__ vct,
                float* __restrict__ logits, short* __restrict__ oattn) {
  const int id = blockIdx.x;
  const int bh = id & 31;                 // XCD-pinned: id%8 == bh%8
  const int qt = id >> 5;
  const int tid = threadIdx.x;
  const int wave = tid >> 6, lane = tid & 63;
  const int l16 = lane & 15, l4 = lane >> 4;

  __shared__ __align__(16) short Ks[2][4096];     // [64 k-rows][64 d], 8KB x2
  __shared__ __align__(16) short Vs[4096];        // [64 d-rows][64 k], 8KB
  __shared__ __align__(16) short attb[4][2048];   // P: [32 q][64 k]/wave, 4KB
  short* const myatt = attb[wave];

  const int qg = qt * 128 + wave * 32;    // wave's q-row base (32 rows)

  const short* qbase = qh + (size_t)bh * 262144 + (size_t)qg * 64;
  const short8 aQ0_0 = *(const short8*)(qbase + (size_t)l16 * 64 + l4 * 8);
  const short8 aQ0_1 = *(const short8*)(qbase + (size_t)l16 * 64 + 32 + l4 * 8);
  const short8 aQ1_0 = *(const short8*)(qbase + (size_t)(16 + l16) * 64 + l4 * 8);
  const short8 aQ1_1 = *(const short8*)(qbase + (size_t)(16 + l16) * 64 + 32 + l4 * 8);

  const short* kb = kc + (size_t)bh * 65536;
  const short* vb = vct + (size_t)bh * 65536;
  float* lgqA = logits + (size_t)bh * 4194304 + (size_t)(qg + l16) * 1024;
  float* lgqB = lgqA + 16 * 1024;

  const int strow = tid >> 3;                    // 0..31
  const int schunk = (tid & 7) ^ (strow & 7);    // pre-swizzled global chunk
  const int sdst = tid * 8;                      // LDS shorts (linear)

  const int sw = (l16 & 7) << 3;          // att/K/V read XOR (elem units)
  float psumA = 0.f, psumB = 0.f;
  f32x4 o0 = {}, o1 = {}, o2 = {}, o3 = {};
  f32x4 o4 = {}, o5 = {}, o6 = {}, o7 = {};

  short* ksc = Ks[0]; short* ksn = Ks[1];

  // ---- prologue: stage K(0) only ----
  #pragma unroll
  for (int ri = 0; ri < 2; ++ri) {
    const int row = ri * 32 + strow;
    async16(kb + (size_t)row * 64 + schunk * 8, ksc + ri * 2048 + sdst);
  }
  asm volatile("s_waitcnt vmcnt(0)" ::: "memory");
  __syncthreads();

  for (int hs = 0; hs < 16; ++hs) {
    const int kbase = hs * 64;

    // ---- stage V(hs) (+ K(hs+1)): loads OLDER than this round's stores ----
    #pragma unroll
    for (int ri = 0; ri < 2; ++ri) {
      const int row = ri * 32 + strow;
      async16(vb + (size_t)row * 1024 + kbase + schunk * 8,
              Vs + ri * 2048 + sdst);
    }
    if (hs < 15) {
      #pragma unroll
      for (int ri = 0; ri < 2; ++ri) {
        const int row = ri * 32 + strow;
        async16(kb + (size_t)(kbase + 64 + row) * 64 + schunk * 8,
                ksn + ri * 2048 + sdst);
      }
    }

    // ---- QK consume on ksc: 4 j-tiles of 16 k ----
    #pragma unroll
    for (int j = 0; j < 4; ++j) {
      const int row = j * 16 + l16;
      short8 k0 = *(const short8*)&ksc[row * 64 + ((l4 ^ (l16 & 7)) << 3)];
      short8 k1 = *(const short8*)&ksc[row * 64 + (((4 + l4) ^ (l16 & 7)) << 3)];
      f32x4 accA = {}, accB = {};
      accA = __builtin_amdgcn_mfma_f32_16x16x32_bf16(k0, aQ0_0, accA, 0, 0, 0);
      accA = __builtin_amdgcn_mfma_f32_16x16x32_bf16(k1, aQ0_1, accA, 0, 0, 0);
      accB = __builtin_amdgcn_mfma_f32_16x16x32_bf16(k0, aQ1_0, accB, 0, 0, 0);
      accB = __builtin_amdgcn_mfma_f32_16x16x32_bf16(k1, aQ1_1, accB, 0, 0, 0);

      *(f32x4*)(lgqA + kbase + j * 16 + l4 * 4) = accA;
      *(f32x4*)(lgqB + kbase + j * 16 + l4 * 4) = accB;

      bf16x4 pA, pB;
      #pragma unroll
      for (int rr = 0; rr < 4; ++rr) {
        const float eA = __expf(accA[rr]);
        const float eB = __expf(accB[rr]);
        psumA += eA;
        psumB += eB;
        pA[rr] = f2bf_hw(eA);
        pB[rr] = f2bf_hw(eB);
      }
      const int pc = (j * 16 + l4 * 4) ^ sw;
      *(bf16x4*)&myatt[l16 * 64 + pc] = pA;
      *(bf16x4*)&myatt[(16 + l16) * 64 + pc] = pB;
    }

    // retire the staging loads (oldest); leave the 8 younger logit stores
    asm volatile("s_waitcnt vmcnt(8)" ::: "memory");
    __syncthreads();                       // V(hs) visible to all waves

    // ---- PV over this 64-k half-section ----
    #pragma unroll
    for (int c = 0; c < 2; ++c) {
      const int cl = (c * 32 + l4 * 8) ^ sw;
      const int vch = ((c * 4 + l4) ^ (l16 & 7)) << 3;
      short8 paA = *(const short8*)&myatt[l16 * 64 + cl];
      short8 paB = *(const short8*)&myatt[(16 + l16) * 64 + cl];
      short8 v0 = *(const short8*)&Vs[(l16) * 64 + vch];
      short8 v1 = *(const short8*)&Vs[(16 + l16) * 64 + vch];
      short8 v2 = *(const short8*)&Vs[(32 + l16) * 64 + vch];
      short8 v3 = *(const short8*)&Vs[(48 + l16) * 64 + vch];
      o0 = __builtin_amdgcn_mfma_f32_16x16x32_bf16(paA, v0, o0, 0, 0, 0);
      o1 = __builtin_amdgcn_mfma_f32_16x16x32_bf16(paA, v1, o1, 0, 0, 0);
      o2 = __builtin_amdgcn_mfma_f32_16x16x32_bf16(paA, v2, o2, 0, 0, 0);
      o3 = __builtin_amdgcn_mfma_f32_16x16x32_bf16(paA, v3, o3, 0, 0, 0);
      o4 = __builtin_amdgcn_mfma_f32_16x16x32_bf16(paB, v0, o4, 0, 0, 0);
      o5 = __builtin_amdgcn_mfma_f32_16x16x32_bf16(paB, v1, o5, 0, 0, 0);
      o6 = __builtin_amdgcn_mfma_f32_16x16x32_bf16(paB, v2, o6, 0, 0, 0);
      o7 = __builtin_amdgcn_mfma_f32_16x16x32_bf16(paB, v3, o7, 0, 0, 0);
    }

    if (hs < 15) {
      __syncthreads();                     // protect Vs/ksc before next stage
      short* t = ksc; ksc = ksn; ksn = t;
    }
  }

  psumA += __shfl_xor(psumA, 16, 64);
  psumA += __shfl_xor(psumA, 32, 64);
  psumB += __shfl_xor(psumB, 16, 64);
  psumB += __shfl_xor(psumB, 32, 64);
  float invA[4], invB[4];
  #pragma unroll
  for (int rr = 0; rr < 4; ++rr) {
    invA[rr] = 1.0f / __shfl(psumA, l4 * 4 + rr, 64);
    invB[rr] = 1.0f / __shfl(psumB, l4 * 4 + rr, 64);
  }

  short* op = oattn + ((size_t)(bh >> 4) * 4096 + qg) * 1024 + (bh & 15) * 64;
  #pragma unroll
  for (int rr = 0; rr < 4; ++rr) {
    const size_t ra = (size_t)(l4 * 4 + rr) * 1024;
    op[ra + l16]      = f2bf(o0[rr] * invA[rr]);
    op[ra + 16 + l16] = f2bf(o1[rr] * invA[rr]);
    op[ra + 32 + l16] = f2bf(o2[rr] * invA[rr]);
    op[ra + 48 + l16] = f2bf(o3[rr] * invA[rr]);
    const size_t rb = (size_t)(16 + l4 * 4 + rr) * 1024;
    op[rb + l16]      = f2bf(o4[rr] * invB[rr]);
    op[rb + 16 + l16] = f2bf(o5[rr] * invB[rr]);
    op[rb + 32 + l16] = f2bf(o6[rr] * invB[rr]);
    op[rb + 48 + l16] = f2bf(o7[rr] * invB[rr]);
  }
}

// ---------------------------------------------------------------------------
extern "C" void kernel_launch(void* const* d_in, const int* in_sizes, int n_in,
                              void* d_out, int out_size, void* d_ws, size_t ws_size,
                              hipStream_t stream) {
  const float* q    = (const float*)d_in[0];
  const float* Wq   = (const float*)d_in[1];
  const float* Wk   = (const float*)d_in[2];
  const float* Wv   = (const float*)d_in[3];
  const float* Wlin = (const float*)d_in[4];
  const float* cw   = (const float*)d_in[5];
  const float* lt   = (const float*)d_in[6];

  float* out_f    = (float*)d_out;             // output 0: [8192][1024] f32
  float* logits_f = out_f + 8388608;           // output 1: [32][4096][1024] f32

  short* ws    = (short*)d_ws;
  short* Wt    = ws;                 // 4 x 1048576
  short* Xb    = ws + 4194304;       // 8388608 ; reused as oattn
  short* QKVq  = ws + 12582912;      // 8388608 head-major Q (pre-scaled)
  short* Kc    = ws + 20971520;      // [32][1024][64]
  short* Vc    = ws + 23068672;      // [32][1024][64]
  short* Vct   = ws + 25165824;      // [32][64][1024]
  short* oattn = Xb;
  // total 27,262,976 shorts = 54.5 MB

  cvt8<<<dim3(4096), 256, 0, stream>>>(q, Xb);

  ConvT4Args ca = { Wq, Wk, Wv, Wlin, Wt };
  convT4<<<dim3(16, 16, 4), 256, 0, stream>>>(ca);

  GemmArgs gq = {};
  gq.A = Xb; gq.Bt = Wt; gq.C = QKVq; gq.C2 = Kc; gq.C3 = Vc;
  gq.sA = 1024; gq.sB = 1024; gq.sC = 0;
  gq.zA = 0; gq.zB = 1048576; gq.zC = 0;
  gq.K = 1024; gq.ltemp = lt; gq.cw = cw; gq.mode = 3;
  gemm_bt<<<dim3(8, 64, 3), 256, 0, stream>>>(gq);

  transpose2d<<<dim3(1, 16, 32), 256, 0, stream>>>(Vc, Vct, 1024, 64);

  fused_attn<<<dim3(1024), 256, 0, stream>>>(QKVq, Kc, Vct, logits_f, oattn);

  GemmArgs gf = {};
  gf.A = oattn; gf.Bt = Wt + 3145728; gf.Cf = out_f;
  gf.sA = 1024; gf.sB = 1024; gf.sC = 1024;
  gf.zA = 0; gf.zB = 0; gf.zC = 0;
  gf.K = 1024; gf.mode = 0;
  gemm_bt<<<dim3(8, 64, 1), 256, 0, stream>>>(gf);
}

// Round 20
// 273.826 us; speedup vs baseline: 1.0480x; 1.0433x over previous
//
#include <hip/hip_runtime.h>
#include <hip/hip_bf16.h>
#include <stdint.h>

// ---------------------------------------------------------------------------
// ConvAttention (B=2,S=4096,HID=1024,H=16,HD=64; conv k=(4,1) stride=(4,1))
// inputs f32, outputs f32; internal compute bf16 (round 3: absmax 0.0625).
// Round-20: r19's V-single-buffer was null/worse -> fused reverted to r17
// (best: 281.5us; K+V double-buffered, 48KB, 3 blocks/CU). New change:
// QKV gemm grid z-interleave -- grid (24,64), zsel = bx%3, ntile = bx/3 ->
// the 3 z-variants of each tile are dispatch-ADJACENT, so each A-panel is
// fetched into L2 once and reused 3x within one residency window (before:
// z-passes 512 slots apart re-read all A from L3, ~32MB extra traffic).
// Pipeline:
//   0. q f32 -> Xb bf16;  1. convT4 W* (one launch)
//   2. merged QKV gemm, z-interleaved (zsel=0 Q x exp(-lt); 1/2 conv Kc/Vc)
//   3. Vc -> Vct;  4. fused attn (r17);  5. out0 = oattn @ Wlin
// ---------------------------------------------------------------------------

using short8 = __attribute__((ext_vector_type(8))) short;
using bf16x4 = __attribute__((ext_vector_type(4))) short;
using f32x4  = __attribute__((ext_vector_type(4))) float;

__device__ __forceinline__ float bf2f(short u) {
  union { float f; uint32_t i; } v; v.i = ((uint32_t)(uint16_t)u) << 16; return v.f;
}
__device__ __forceinline__ short f2bf(float f) {
  union { float f; uint32_t i; } v; v.f = f;
  uint32_t r = v.i + 0x7FFFu + ((v.i >> 16) & 1u);   // RNE
  return (short)(uint16_t)(r >> 16);
}
__device__ __forceinline__ short f2bf_hw(float f) {
  __hip_bfloat16 h = __float2bfloat16(f);             // hw cvt, pairs fuse
  return *reinterpret_cast<short*>(&h);
}

__device__ __forceinline__ void async16(const void* g, void* l) {
  __builtin_amdgcn_global_load_lds(
      (const __attribute__((address_space(1))) void*)g,
      (__attribute__((address_space(3))) void*)l, 16, 0, 0);
}

// ---------------------------------------------------------------------------
__global__ void cvt8(const float* __restrict__ in, short* __restrict__ out) {
  const size_t i = ((size_t)blockIdx.x * 256 + threadIdx.x) * 8;
  float4 a = *(const float4*)(in + i);
  float4 b = *(const float4*)(in + i + 4);
  short8 o;
  o[0] = f2bf(a.x); o[1] = f2bf(a.y); o[2] = f2bf(a.z); o[3] = f2bf(a.w);
  o[4] = f2bf(b.x); o[5] = f2bf(b.y); o[6] = f2bf(b.z); o[7] = f2bf(b.w);
  *(short8*)(out + i) = o;
}

// ---------------------------------------------------------------------------
struct ConvT4Args { const float* s0; const float* s1; const float* s2;
                    const float* s3; short* out; };
__global__ void convT4(ConvT4Args a) {
  __shared__ float tile[64][65];
  const float* in = (blockIdx.z == 0) ? a.s0 : (blockIdx.z == 1) ? a.s1
                   : (blockIdx.z == 2) ? a.s2 : a.s3;
  short* out = a.out + (size_t)blockIdx.z * 1048576;
  const int c0 = blockIdx.x * 64, r0 = blockIdx.y * 64;
  const int tx = threadIdx.x & 63, ty = threadIdx.x >> 6;
  #pragma unroll
  for (int i = ty; i < 64; i += 4)
    tile[i][tx] = in[(size_t)(r0 + i) * 1024 + c0 + tx];
  __syncthreads();
  #pragma unroll
  for (int i = ty; i < 64; i += 4)
    out[(size_t)(c0 + i) * 1024 + r0 + tx] = f2bf(tile[tx][i]);
}

// ---------------------------------------------------------------------------
__global__ void transpose2d(const short* __restrict__ in, short* __restrict__ out,
                            int R, int C) {
  __shared__ short tile[64][65];
  const size_t zoff = (size_t)blockIdx.z * (size_t)R * (size_t)C;
  const int c0 = blockIdx.x * 64, r0 = blockIdx.y * 64;
  const int tx = threadIdx.x & 63, ty = threadIdx.x >> 6;
  #pragma unroll
  for (int i = ty; i < 64; i += 4)
    tile[i][tx] = in[zoff + (size_t)(r0 + i) * C + c0 + tx];
  __syncthreads();
  #pragma unroll
  for (int i = ty; i < 64; i += 4)
    out[zoff + (size_t)(c0 + i) * R + r0 + tx] = tile[tx][i];
}

// ---------------------------------------------------------------------------
// C = A[M][K] * Bt[N][K]^T, bf16 inputs, f32 accum. 128x128 tile, BK=64.
// mode 0: f32 row-major -> Cf (grid x = n-tile)
// mode 3: merged QKV, z-interleaved grid (24,64): zsel = bx%3, ntile = bx/3.
//         zsel=0 head-major bf16 x exp(-lt); zsel=1/2 conv -> Kc/Vc
struct GemmArgs {
  const short* A; const short* Bt;
  short* C; short* C2; short* C3; float* Cf;
  long sA, sB, sC;
  long zA, zB, zC;
  int  K;
  const float* ltemp;
  const float* cw;
  int  mode;
};

__global__ __launch_bounds__(256, 2)
void gemm_bt(GemmArgs g) {
  const int tid  = threadIdx.x;
  const int wave = tid >> 6, lane = tid & 63;
  const int l16 = lane & 15, l4 = lane >> 4;
  const int wm = wave & 1, wn = wave >> 1;

  int nt = blockIdx.x, zsel = blockIdx.z;
  if (g.mode == 3) { zsel = blockIdx.x % 3; nt = blockIdx.x / 3; }
  const int m0 = blockIdx.y * 128, n0 = nt * 128;
  const size_t zA = (size_t)zsel * g.zA;
  const size_t zB = (size_t)zsel * g.zB;
  const size_t zC = (size_t)zsel * g.zC;

  __shared__ __align__(16) short As[128 * 64];
  __shared__ __align__(16) short Bs[128 * 64];

  f32x4 acc[4][4] = {};

  const int srow = tid >> 3;
  const int scol = (tid & 7) << 3;
  const short* Abase = g.A + zA + (size_t)m0 * g.sA + scol;
  const short* Bbase = g.Bt + zB + (size_t)n0 * g.sB + scol;

  for (int k0 = 0; k0 < g.K; k0 += 64) {
    __syncthreads();
    #pragma unroll
    for (int c = 0; c < 4; ++c) {
      async16(Abase + (size_t)(c * 32 + srow) * g.sA + k0, &As[c * 2048 + wave * 512]);
      async16(Bbase + (size_t)(c * 32 + srow) * g.sB + k0, &Bs[c * 2048 + wave * 512]);
    }
    asm volatile("s_waitcnt vmcnt(0)" ::: "memory");
    __syncthreads();
    #pragma unroll
    for (int kk = 0; kk < 2; ++kk) {
      short8 a[4], b[4];
      #pragma unroll
      for (int t = 0; t < 4; ++t) {
        a[t] = *(const short8*)&As[(wm * 64 + t * 16 + l16) * 64 + kk * 32 + l4 * 8];
        b[t] = *(const short8*)&Bs[(wn * 64 + t * 16 + l16) * 64 + kk * 32 + l4 * 8];
      }
      #pragma unroll
      for (int i = 0; i < 4; ++i)
        #pragma unroll
        for (int j = 0; j < 4; ++j)
          acc[i][j] = __builtin_amdgcn_mfma_f32_16x16x32_bf16(a[i], b[j], acc[i][j], 0, 0, 0);
    }
  }

  if (g.mode == 0) {
    float* Cz = g.Cf + zC;
    #pragma unroll
    for (int i = 0; i < 4; ++i) {
      const int row = m0 + wm * 64 + i * 16 + l4 * 4;
      #pragma unroll
      for (int j = 0; j < 4; ++j) {
        const int col = n0 + wn * 64 + j * 16 + l16;
        #pragma unroll
        for (int rr = 0; rr < 4; ++rr)
          Cz[(size_t)(row + rr) * g.sC + col] = acc[i][j][rr];
      }
    }
  } else if (zsel == 0) {
    float sc = __expf(-g.ltemp[0]);
    short* Cz = g.C;
    #pragma unroll
    for (int i = 0; i < 4; ++i) {
      const int row = m0 + wm * 64 + i * 16 + l4 * 4;
      #pragma unroll
      for (int j = 0; j < 4; ++j) {
        const int col = n0 + wn * 64 + j * 16 + l16;
        const int hh = col >> 6, dd = col & 63;
        #pragma unroll
        for (int rr = 0; rr < 4; ++rr) {
          const int m = row + rr;
          const size_t off = (size_t)((m >> 12) * 16 + hh) * 262144
                           + (size_t)(m & 4095) * 64 + dd;
          Cz[off] = f2bf(acc[i][j][rr] * sc);
        }
      }
    }
  } else {
    const int h = (n0 + wn * 64) >> 6;
    float wv[4];
    #pragma unroll
    for (int t = 0; t < 4; ++t) wv[t] = g.cw[h * 4 + t];
    short* dst = (zsel == 1) ? g.C2 : g.C3;
    #pragma unroll
    for (int i = 0; i < 4; ++i) {
      const int row_base = m0 + wm * 64 + i * 16 + l4 * 4;
      const int b  = row_base >> 12;
      const int sk = (row_base & 4095) >> 2;
      #pragma unroll
      for (int j = 0; j < 4; ++j) {
        const int d = j * 16 + l16;
        float v = wv[0] * acc[i][j][0] + wv[1] * acc[i][j][1]
                + wv[2] * acc[i][j][2] + wv[3] * acc[i][j][3];
        dst[(size_t)(b * 16 + h) * 65536 + (size_t)sk * 64 + d] = f2bf(v);
      }
    }
  }
}

// ---------------------------------------------------------------------------
// fused logits + max-free softmax + PV with block-shared LDS K/V staging
// (r17 exactly — best measured). grid 1024 (bh = id&31 XCD-pinned);
// block = 128 q. 16 half-sections of 64 k, K+V double-buffered; stage loads
// issued BEFORE the consume phase's stores -> vmcnt(8) retires loads,
// leaves stores in flight. LDS 48KB -> 3 blocks/CU.
__global__ __launch_bounds__(256, 3)
void fused_attn(const short* __restrict__ qh, const short* __restrict__ kc,
                const short* __restrict__ vct,
                float* __restrict__ logits, short* __restrict__ oattn) {
  const int id = blockIdx.x;
  const int bh = id & 31;                 // XCD-pinned: id%8 == bh%8
  const int qt = id >> 5;
  const int tid = threadIdx.x;
  const int wave = tid >> 6, lane = tid & 63;
  const int l16 = lane & 15, l4 = lane >> 4;

  __shared__ __align__(16) short Ks[2][4096];     // [64 k-rows][64 d], 8KB x2
  __shared__ __align__(16) short Vs[2][4096];     // [64 d-rows][64 k], 8KB x2
  __shared__ __align__(16) short attb[4][2048];   // P: [32 q][64 k]/wave, 4KB
  short* const myatt = attb[wave];

  const int qg = qt * 128 + wave * 32;    // wave's q-row base (32 rows)

  const short* qbase = qh + (size_t)bh * 262144 + (size_t)qg * 64;
  const short8 aQ0_0 = *(const short8*)(qbase + (size_t)l16 * 64 + l4 * 8);
  const short8 aQ0_1 = *(const short8*)(qbase + (size_t)l16 * 64 + 32 + l4 * 8);
  const short8 aQ1_0 = *(const short8*)(qbase + (size_t)(16 + l16) * 64 + l4 * 8);
  const short8 aQ1_1 = *(const short8*)(qbase + (size_t)(16 + l16) * 64 + 32 + l4 * 8);

  const short* kb = kc + (size_t)bh * 65536;
  const short* vb = vct + (size_t)bh * 65536;
  float* lgqA = logits + (size_t)bh * 4194304 + (size_t)(qg + l16) * 1024;
  float* lgqB = lgqA + 16 * 1024;

  const int strow = tid >> 3;                    // 0..31
  const int schunk = (tid & 7) ^ (strow & 7);    // pre-swizzled global chunk
  const int sdst = tid * 8;                      // LDS shorts (linear)

  const int sw = (l16 & 7) << 3;          // att/K/V read XOR (elem units)
  float psumA = 0.f, psumB = 0.f;
  f32x4 o0 = {}, o1 = {}, o2 = {}, o3 = {};
  f32x4 o4 = {}, o5 = {}, o6 = {}, o7 = {};

  short* ksc = Ks[0]; short* ksn = Ks[1];
  short* vsc = Vs[0]; short* vsn = Vs[1];

  #pragma unroll
  for (int ri = 0; ri < 2; ++ri) {
    const int row = ri * 32 + strow;
    async16(kb + (size_t)row * 64 + schunk * 8, ksc + ri * 2048 + sdst);
    async16(vb + (size_t)row * 1024 + schunk * 8, vsc + ri * 2048 + sdst);
  }
  asm volatile("s_waitcnt vmcnt(0)" ::: "memory");
  __syncthreads();

  for (int hs = 0; hs < 16; ++hs) {
    const int kbase = hs * 64;

    if (hs < 15) {
      #pragma unroll
      for (int ri = 0; ri < 2; ++ri) {
        const int row = ri * 32 + strow;
        async16(kb + (size_t)(kbase + 64 + row) * 64 + schunk * 8,
                ksn + ri * 2048 + sdst);
        async16(vb + (size_t)row * 1024 + (kbase + 64) + schunk * 8,
                vsn + ri * 2048 + sdst);
      }
    }

    #pragma unroll
    for (int j = 0; j < 4; ++j) {
      const int row = j * 16 + l16;
      short8 k0 = *(const short8*)&ksc[row * 64 + ((l4 ^ (l16 & 7)) << 3)];
      short8 k1 = *(const short8*)&ksc[row * 64 + (((4 + l4) ^ (l16 & 7)) << 3)];
      f32x4 accA = {}, accB = {};
      accA = __builtin_amdgcn_mfma_f32_16x16x32_bf16(k0, aQ0_0, accA, 0, 0, 0);
      accA = __builtin_amdgcn_mfma_f32_16x16x32_bf16(k1, aQ0_1, accA, 0, 0, 0);
      accB = __builtin_amdgcn_mfma_f32_16x16x32_bf16(k0, aQ1_0, accB, 0, 0, 0);
      accB = __builtin_amdgcn_mfma_f32_16x16x32_bf16(k1, aQ1_1, accB, 0, 0, 0);

      *(f32x4*)(lgqA + kbase + j * 16 + l4 * 4) = accA;
      *(f32x4*)(lgqB + kbase + j * 16 + l4 * 4) = accB;

      bf16x4 pA, pB;
      #pragma unroll
      for (int rr = 0; rr < 4; ++rr) {
        const float eA = __expf(accA[rr]);
        const float eB = __expf(accB[rr]);
        psumA += eA;
        psumB += eB;
        pA[rr] = f2bf_hw(eA);
        pB[rr] = f2bf_hw(eB);
      }
      const int pc = (j * 16 + l4 * 4) ^ sw;
      *(bf16x4*)&myatt[l16 * 64 + pc] = pA;
      *(bf16x4*)&myatt[(16 + l16) * 64 + pc] = pB;
    }

    #pragma unroll
    for (int c = 0; c < 2; ++c) {
      const int cl = (c * 32 + l4 * 8) ^ sw;
      const int vch = ((c * 4 + l4) ^ (l16 & 7)) << 3;
      short8 paA = *(const short8*)&myatt[l16 * 64 + cl];
      short8 paB = *(const short8*)&myatt[(16 + l16) * 64 + cl];
      short8 v0 = *(const short8*)&vsc[(l16) * 64 + vch];
      short8 v1 = *(const short8*)&vsc[(16 + l16) * 64 + vch];
      short8 v2 = *(const short8*)&vsc[(32 + l16) * 64 + vch];
      short8 v3 = *(const short8*)&vsc[(48 + l16) * 64 + vch];
      o0 = __builtin_amdgcn_mfma_f32_16x16x32_bf16(paA, v0, o0, 0, 0, 0);
      o1 = __builtin_amdgcn_mfma_f32_16x16x32_bf16(paA, v1, o1, 0, 0, 0);
      o2 = __builtin_amdgcn_mfma_f32_16x16x32_bf16(paA, v2, o2, 0, 0, 0);
      o3 = __builtin_amdgcn_mfma_f32_16x16x32_bf16(paA, v3, o3, 0, 0, 0);
      o4 = __builtin_amdgcn_mfma_f32_16x16x32_bf16(paB, v0, o4, 0, 0, 0);
      o5 = __builtin_amdgcn_mfma_f32_16x16x32_bf16(paB, v1, o5, 0, 0, 0);
      o6 = __builtin_amdgcn_mfma_f32_16x16x32_bf16(paB, v2, o6, 0, 0, 0);
      o7 = __builtin_amdgcn_mfma_f32_16x16x32_bf16(paB, v3, o7, 0, 0, 0);
    }

    if (hs < 15) {
      asm volatile("s_waitcnt vmcnt(8)" ::: "memory");
      __syncthreads();
      short* t;
      t = ksc; ksc = ksn; ksn = t;
      t = vsc; vsc = vsn; vsn = t;
    }
  }

  psumA += __shfl_xor(psumA, 16, 64);
  psumA += __shfl_xor(psumA, 32, 64);
  psumB += __shfl_xor(psumB, 16, 64);
  psumB += __shfl_xor(psumB, 32, 64);
  float invA[4], invB[4];
  #pragma unroll
  for (int rr = 0; rr < 4; ++rr) {
    invA[rr] = 1.0f / __shfl(psumA, l4 * 4 + rr, 64);
    invB[rr] = 1.0f / __shfl(psumB, l4 * 4 + rr, 64);
  }

  short* op = oattn + ((size_t)(bh >> 4) * 4096 + qg) * 1024 + (bh & 15) * 64;
  #pragma unroll
  for (int rr = 0; rr < 4; ++rr) {
    const size_t ra = (size_t)(l4 * 4 + rr) * 1024;
    op[ra + l16]      = f2bf(o0[rr] * invA[rr]);
    op[ra + 16 + l16] = f2bf(o1[rr] * invA[rr]);
    op[ra + 32 + l16] = f2bf(o2[rr] * invA[rr]);
    op[ra + 48 + l16] = f2bf(o3[rr] * invA[rr]);
    const size_t rb = (size_t)(16 + l4 * 4 + rr) * 1024;
    op[rb + l16]      = f2bf(o4[rr] * invB[rr]);
    op[rb + 16 + l16] = f2bf(o5[rr] * invB[rr]);
    op[rb + 32 + l16] = f2bf(o6[rr] * invB[rr]);
    op[rb + 48 + l16] = f2bf(o7[rr] * invB[rr]);
  }
}

// ---------------------------------------------------------------------------
extern "C" void kernel_launch(void* const* d_in, const int* in_sizes, int n_in,
                              void* d_out, int out_size, void* d_ws, size_t ws_size,
                              hipStream_t stream) {
  const float* q    = (const float*)d_in[0];
  const float* Wq   = (const float*)d_in[1];
  const float* Wk   = (const float*)d_in[2];
  const float* Wv   = (const float*)d_in[3];
  const float* Wlin = (const float*)d_in[4];
  const float* cw   = (const float*)d_in[5];
  const float* lt   = (const float*)d_in[6];

  float* out_f    = (float*)d_out;             // output 0: [8192][1024] f32
  float* logits_f = out_f + 8388608;           // output 1: [32][4096][1024] f32

  short* ws    = (short*)d_ws;
  short* Wt    = ws;                 // 4 x 1048576
  short* Xb    = ws + 4194304;       // 8388608 ; reused as oattn
  short* QKVq  = ws + 12582912;      // 8388608 head-major Q (pre-scaled)
  short* Kc    = ws + 20971520;      // [32][1024][64]
  short* Vc    = ws + 23068672;      // [32][1024][64]
  short* Vct   = ws + 25165824;      // [32][64][1024]
  short* oattn = Xb;
  // total 27,262,976 shorts = 54.5 MB

  cvt8<<<dim3(4096), 256, 0, stream>>>(q, Xb);

  ConvT4Args ca = { Wq, Wk, Wv, Wlin, Wt };
  convT4<<<dim3(16, 16, 4), 256, 0, stream>>>(ca);

  // merged QKV projections, z-interleaved grid (24,64): zsel = bx%3
  GemmArgs gq = {};
  gq.A = Xb; gq.Bt = Wt; gq.C = QKVq; gq.C2 = Kc; gq.C3 = Vc;
  gq.sA = 1024; gq.sB = 1024; gq.sC = 0;
  gq.zA = 0; gq.zB = 1048576; gq.zC = 0;
  gq.K = 1024; gq.ltemp = lt; gq.cw = cw; gq.mode = 3;
  gemm_bt<<<dim3(24, 64, 1), 256, 0, stream>>>(gq);

  transpose2d<<<dim3(1, 16, 32), 256, 0, stream>>>(Vc, Vct, 1024, 64);

  fused_attn<<<dim3(1024), 256, 0, stream>>>(QKVq, Kc, Vct, logits_f, oattn);

  GemmArgs gf = {};
  gf.A = oattn; gf.Bt = Wt + 3145728; gf.Cf = out_f;
  gf.sA = 1024; gf.sB = 1024; gf.sC = 1024;
  gf.zA = 0; gf.zB = 0; gf.zC = 0;
  gf.K = 1024; gf.mode = 0;
  gemm_bt<<<dim3(8, 64, 1), 256, 0, stream>>>(gf);
}